// Round 5
// baseline (287.884 us; speedup 1.0000x reference)
//
#include <hip/hip_runtime.h>

#define B_DIM 4
#define T_DIM 4096
#define C_DIM 2048
#define KK 4
#define C4 (C_DIM / 4)                 // 512 float4 per row
#define ROWS (B_DIM * T_DIM)           // 16384 rows
#define NV4 (ROWS * C4)                // 8388608 float4 elements
#define BLOCK 256
#define NBLK (NV4 / BLOCK)             // 32768 blocks
#define NXCD 8
#define BPX (NBLK / NXCD)              // 4096 blocks per XCD chunk

typedef float v4f __attribute__((ext_vector_type(4)));

// R5: copy-identical address streams. Five schedule/concurrency variants all
// pinned at 2.55-2.64 TB/s; the known 6.3+ TB/s kernels (fillBuffer, float4
// copy) differ only in address pattern: linear wave-contiguous streams vs our
// 1KB@8KB-stride scatter. Here: thread == linear float4 index (TT=1). The
// wave's main load is 1KB contiguous; taps t-1..t-3 are three more linear
// streams at -8/-16/-24KB, which a bijective XCD swizzle (contiguous 16MB
// chunk per XCD) makes L2-local (fetched by blocks ~2-6 earlier on the SAME
// XCD). HBM traffic stays ~134MB in + 134MB out; read amplification is
// absorbed by per-XCD L2. t is wave-uniform (64 lanes within one row), so
// halo predication is uniform-branch cheap.
__global__ __launch_bounds__(256) void canonconv_kernel(
    const float* __restrict__ x,
    const float* __restrict__ w,
    const float* __restrict__ bias,
    float* __restrict__ out)
{
    // bijective XCD swizzle: dispatch round-robins bid across 8 XCDs, so
    // bid%8 is the XCD; give each XCD a contiguous address chunk.
    const int bid = blockIdx.x;
    const int swz = (bid & (NXCD - 1)) * BPX + (bid >> 3);
    const int p   = swz * BLOCK + threadIdx.x;   // linear float4 index
    const int c4  = p & (C4 - 1);
    const int row = p >> 9;                      // p / 512
    const int t   = row & (T_DIM - 1);           // row % 4096 (t within batch)
    const int c   = c4 * 4;

    const v4f* xv = (const v4f*)x;

    // --- x streams: main + 3 tap rows (all linear; halo rows wave-uniform)
    const v4f xc = xv[p];
    v4f xm1 = (v4f)0.0f, xm2 = (v4f)0.0f, xm3 = (v4f)0.0f;
    if (t >= 1) xm1 = xv[p - C4];
    if (t >= 2) xm2 = xv[p - 2 * C4];
    if (t >= 3) xm3 = xv[p - 3 * C4];

    // --- weights/bias (L1-resident: ~20KB region per block)
    const v4f* wv = (const v4f*)(w + (size_t)c * KK);
    const v4f a0 = wv[0];  // (w[c,0], w[c,1], w[c,2], w[c,3])
    const v4f a1 = wv[1];
    const v4f a2 = wv[2];
    const v4f a3 = wv[3];
    const v4f bv = *(const v4f*)(bias + c);

    // per-tap coefficient vectors; x[t]-tap fused with residual (1 + w[c,3])
    v4f r;
    r.x = fmaf(xc.x, 1.0f + a0.w, fmaf(xm1.x, a0.z, fmaf(xm2.x, a0.y, fmaf(xm3.x, a0.x, bv.x))));
    r.y = fmaf(xc.y, 1.0f + a1.w, fmaf(xm1.y, a1.z, fmaf(xm2.y, a1.y, fmaf(xm3.y, a1.x, bv.y))));
    r.z = fmaf(xc.z, 1.0f + a2.w, fmaf(xm1.z, a2.z, fmaf(xm2.z, a2.y, fmaf(xm3.z, a2.x, bv.z))));
    r.w = fmaf(xc.w, 1.0f + a3.w, fmaf(xm1.w, a3.z, fmaf(xm2.w, a3.y, fmaf(xm3.w, a3.x, bv.w))));

    ((v4f*)out)[p] = r;
}

extern "C" void kernel_launch(void* const* d_in, const int* in_sizes, int n_in,
                              void* d_out, int out_size, void* d_ws, size_t ws_size,
                              hipStream_t stream) {
    const float* x    = (const float*)d_in[0];
    const float* w    = (const float*)d_in[1];
    const float* bias = (const float*)d_in[2];
    float* out = (float*)d_out;

    canonconv_kernel<<<NBLK, BLOCK, 0, stream>>>(x, w, bias, out);
}

// Round 6
// 255.111 us; speedup vs baseline: 1.1285x; 1.1285x over previous
//
#include <hip/hip_runtime.h>

#define B_DIM 4
#define T_DIM 4096
#define C_DIM 2048
#define KK 4
#define C4 (C_DIM / 4)                 // 512 float4 per row
#define ROWS (B_DIM * T_DIM)           // 16384 rows
#define NV4 (ROWS * C4)                // 8388608 float4 elements
#define BLOCK 256
#define NBLK 2048                      // same residency shape as the 82us baseline
#define NTHREADS (NBLK * BLOCK)        // 524288
#define ITERS (NV4 / NTHREADS)         // 16 block-stride iterations, +8MB each

typedef float v4f __attribute__((ext_vector_type(4)));

// R6: deconfounded linear-stream experiment. R5 regressed (130us) but changed
// three things at once: address map, 16x more one-shot waves with per-output
// weight refetch (~670MB extra requests), and an unverified bid%8 XCD-swizzle
// whose failure would temporally separate each x-line's 4 readers -> 4x HBM
// fetch (130us matches ~670MB at ~5TB/s). This version keeps ONLY the linear
// map: m13-copy block-stride structure (2048 blocks, 16 iters), weights/bias
// hoisted (stride is a multiple of C4 so c4 is iteration-invariant), no
// swizzle. Within an iteration the 4 readers of any line are blocks
// bid,bid+2,bid+4,bid+6 — dispatch-adjacent and concurrent -> taps are L2/L3
// hits with no assumptions about XCD mapping. Single variable vs the 82us
// baseline: wave-contiguous linear streams vs 1KB@8KB-stride scatter.
__global__ __launch_bounds__(256) void canonconv_kernel(
    const float* __restrict__ x,
    const float* __restrict__ w,
    const float* __restrict__ bias,
    float* __restrict__ out)
{
    const int tid = blockIdx.x * BLOCK + threadIdx.x;
    const int c4  = tid & (C4 - 1);     // iteration-invariant channel group
    const int c   = c4 * 4;

    // --- weights/bias once per thread (L1/L2-resident region)
    const v4f* wv = (const v4f*)(w + (size_t)c * KK);
    const v4f a0 = wv[0];  // (w[c,0], w[c,1], w[c,2], w[c,3])
    const v4f a1 = wv[1];
    const v4f a2 = wv[2];
    const v4f a3 = wv[3];
    const v4f bv = *(const v4f*)(bias + c);

    // per-tap coefficients, x[t]-tap fused with residual (1 + w[c,3])
    v4f tap0, tap1, tap2, tap3;
    tap0.x = a0.x; tap0.y = a1.x; tap0.z = a2.x; tap0.w = a3.x; // x[t-3]
    tap1.x = a0.y; tap1.y = a1.y; tap1.z = a2.y; tap1.w = a3.y; // x[t-2]
    tap2.x = a0.z; tap2.y = a1.z; tap2.z = a2.z; tap2.w = a3.z; // x[t-1]
    tap3.x = 1.0f + a0.w; tap3.y = 1.0f + a1.w; tap3.z = 1.0f + a2.w; tap3.w = 1.0f + a3.w;

    const v4f* xv = (const v4f*)x;
    v4f*       ov = (v4f*)out;

    #pragma unroll 1   // rolled: continuous copy-like stream, bounded VGPR
    for (int iter = 0; iter < ITERS; ++iter) {
        const int p   = tid + iter * NTHREADS;   // linear float4 index
        const int row = p >> 9;                  // wave-uniform (64 lanes in one row)
        const int t   = row & (T_DIM - 1);       // t within batch

        const v4f xc = xv[p];
        v4f xm1 = (v4f)0.0f, xm2 = (v4f)0.0f, xm3 = (v4f)0.0f;
        if (t >= 1) xm1 = xv[p - C4];            // wave-uniform branches
        if (t >= 2) xm2 = xv[p - 2 * C4];
        if (t >= 3) xm3 = xv[p - 3 * C4];

        v4f r;
        r.x = fmaf(xc.x, tap3.x, fmaf(xm1.x, tap2.x, fmaf(xm2.x, tap1.x, fmaf(xm3.x, tap0.x, bv.x))));
        r.y = fmaf(xc.y, tap3.y, fmaf(xm1.y, tap2.y, fmaf(xm2.y, tap1.y, fmaf(xm3.y, tap0.y, bv.y))));
        r.z = fmaf(xc.z, tap3.z, fmaf(xm1.z, tap2.z, fmaf(xm2.z, tap1.z, fmaf(xm3.z, tap0.z, bv.z))));
        r.w = fmaf(xc.w, tap3.w, fmaf(xm1.w, tap2.w, fmaf(xm2.w, tap1.w, fmaf(xm3.w, tap0.w, bv.w))));

        ov[p] = r;
    }
}

extern "C" void kernel_launch(void* const* d_in, const int* in_sizes, int n_in,
                              void* d_out, int out_size, void* d_ws, size_t ws_size,
                              hipStream_t stream) {
    const float* x    = (const float*)d_in[0];
    const float* w    = (const float*)d_in[1];
    const float* bias = (const float*)d_in[2];
    float* out = (float*)d_out;

    canonconv_kernel<<<NBLK, BLOCK, 0, stream>>>(x, w, bias, out);
}

// Round 7
// 236.988 us; speedup vs baseline: 1.2148x; 1.0765x over previous
//
#include <hip/hip_runtime.h>

#define B_DIM 4
#define T_DIM 4096
#define C_DIM 2048
#define KK 4
#define C4 (C_DIM / 4)        // 512 float4 per row (8 KB row)
#define ROWS (B_DIM * T_DIM)  // 16384 rows
#define BLOCK 512             // one thread per float4 column -> one row per load round
#define RR 16                 // rows per block; halo amp = 3/16
#define NBLK (ROWS / RR)      // 1024 blocks

typedef float v4f __attribute__((ext_vector_type(4)));

// R7: dense-linear streams (R6-proven >=4.17 TB/s vs 2.6 for strided scatter)
// WITH register-carried recurrence so tap bytes are never refetched (R6's
// FETCH was 2x input: cross-block tap sharing failed across XCD L2s). Each
// block owns 16 contiguous whole rows; 512 threads = full 8 KB row per load
// round; thread tid owns column c4=tid and shift-registers xm1..xm3 across
// rows. Every x-line is loaded exactly once by exactly one block (+3 halo
// rows per 16). Both streams (read, write) are dense and sequential per
// block. FETCH ~156 MB by construction — no cache or XCD-mapping assumptions.
// 4096 % RR == 0 so a block never crosses a batch boundary; t0 is
// block-uniform so halo predication is a uniform branch.
__global__ __launch_bounds__(512) void canonconv_kernel(
    const float* __restrict__ x,
    const float* __restrict__ w,
    const float* __restrict__ bias,
    float* __restrict__ out)
{
    const int c4   = threadIdx.x;          // 0..511: this thread's float4 column
    const int row0 = blockIdx.x * RR;      // first row of this block's run
    const int t0   = row0 & (T_DIM - 1);   // t within batch (block-uniform)
    const int c    = c4 * 4;

    // --- weights/bias once per thread (16 KB + 8 KB region: L1/L2-resident)
    const v4f* wv = (const v4f*)(w + (size_t)c * KK);
    const v4f a0 = wv[0];  // (w[c,0], w[c,1], w[c,2], w[c,3])
    const v4f a1 = wv[1];
    const v4f a2 = wv[2];
    const v4f a3 = wv[3];
    const v4f bv = *(const v4f*)(bias + c);

    // per-tap coefficients; x[t]-tap fused with residual (1 + w[c,3])
    v4f tap0, tap1, tap2, tap3;
    tap0.x = a0.x; tap0.y = a1.x; tap0.z = a2.x; tap0.w = a3.x; // x[t-3]
    tap1.x = a0.y; tap1.y = a1.y; tap1.z = a2.y; tap1.w = a3.y; // x[t-2]
    tap2.x = a0.z; tap2.y = a1.z; tap2.z = a2.z; tap2.w = a3.z; // x[t-1]
    tap3.x = 1.0f + a0.w; tap3.y = 1.0f + a1.w; tap3.z = 1.0f + a2.w; tap3.w = 1.0f + a3.w;

    const v4f* xp = (const v4f*)x + (size_t)row0 * C4 + c4;
    v4f*       op = (v4f*)out     + (size_t)row0 * C4 + c4;

    // --- halo: previous 3 rows (zeros before t=0; block-uniform branch)
    v4f xm1, xm2, xm3;
    if (t0 != 0) {
        xm3 = xp[-3 * C4];
        xm2 = xp[-2 * C4];
        xm1 = xp[-1 * C4];
    } else {
        xm3 = (v4f)0.0f;
        xm2 = (v4f)0.0f;
        xm1 = (v4f)0.0f;
    }

    // --- march RR rows: one dense 8 KB row load + one dense row store each.
    // Recurrence carried in registers; no byte is ever fetched twice.
    #pragma unroll
    for (int j = 0; j < RR; ++j) {
        const v4f xc = xp[j * C4];
        v4f r;
        r.x = fmaf(xc.x, tap3.x, fmaf(xm1.x, tap2.x, fmaf(xm2.x, tap1.x, fmaf(xm3.x, tap0.x, bv.x))));
        r.y = fmaf(xc.y, tap3.y, fmaf(xm1.y, tap2.y, fmaf(xm2.y, tap1.y, fmaf(xm3.y, tap0.y, bv.y))));
        r.z = fmaf(xc.z, tap3.z, fmaf(xm1.z, tap2.z, fmaf(xm2.z, tap1.z, fmaf(xm3.z, tap0.z, bv.z))));
        r.w = fmaf(xc.w, tap3.w, fmaf(xm1.w, tap2.w, fmaf(xm2.w, tap1.w, fmaf(xm3.w, tap0.w, bv.w))));
        op[j * C4] = r;
        xm3 = xm2;
        xm2 = xm1;
        xm1 = xc;
    }
}

extern "C" void kernel_launch(void* const* d_in, const int* in_sizes, int n_in,
                              void* d_out, int out_size, void* d_ws, size_t ws_size,
                              hipStream_t stream) {
    const float* x    = (const float*)d_in[0];
    const float* w    = (const float*)d_in[1];
    const float* bias = (const float*)d_in[2];
    float* out = (float*)d_out;

    canonconv_kernel<<<NBLK, BLOCK, 0, stream>>>(x, w, bias, out);
}